// Round 8
// baseline (217.132 us; speedup 1.0000x reference)
//
#include <hip/hip_runtime.h>
#include <hip/hip_bf16.h>

#define M 8192
#define N 8192
#define K 512
#define BM 256
#define BN 128
#define BK 32
#define NS 16    // K slices per tile
#define NTILE 8  // col tiles per block

typedef __attribute__((ext_vector_type(8))) short bf16x8;
typedef __attribute__((ext_vector_type(4))) float f32x4;
typedef __attribute__((ext_vector_type(8))) unsigned short us8;

__device__ inline void gload_lds16(const void* g, void* l) {
  __builtin_amdgcn_global_load_lds(
      (const __attribute__((address_space(1))) unsigned int*)g,
      (__attribute__((address_space(3))) unsigned int*)l, 16, 0, 0);
}

// Pin VMEM issue order across this point.
#define MEMFENCE() asm volatile("" ::: "memory")

#define BARRIER()                          \
  do {                                     \
    asm volatile("" ::: "memory");         \
    __builtin_amdgcn_s_barrier();          \
    asm volatile("" ::: "memory");         \
  } while (0)

// Fused prep: cast f32 rows -> bf16, store INVERSE L2 norm (1/max(norm,1e-4)).
// Norms are ~sqrt(512); inv1*inv2 == 1/max(w1*w2,1e-8) exactly here.
__global__ __launch_bounds__(256) void prep_kernel(const float* __restrict__ img,
                                                   const float* __restrict__ txt,
                                                   unsigned short* __restrict__ Abf,
                                                   unsigned short* __restrict__ Bbf,
                                                   float* __restrict__ w1,
                                                   float* __restrict__ w2) {
  const int half = blockIdx.x >> 11;
  const int lb = blockIdx.x & 2047;
  const float* in = half ? txt : img;
  unsigned short* outb = half ? Bbf : Abf;
  float* norms = half ? w2 : w1;

  const int gw = (lb * 256 + threadIdx.x) >> 6;
  const int lane = threadIdx.x & 63;
  const float4* rp4 = (const float4*)(in + (size_t)gw * K);
  float4 v0 = rp4[lane * 2];
  float4 v1 = rp4[lane * 2 + 1];
  float ss = v0.x * v0.x + v0.y * v0.y + v0.z * v0.z + v0.w * v0.w +
             v1.x * v1.x + v1.y * v1.y + v1.z * v1.z + v1.w * v1.w;
  float f[8] = {v0.x, v0.y, v0.z, v0.w, v1.x, v1.y, v1.z, v1.w};
  us8 o;
#pragma unroll
  for (int i = 0; i < 8; ++i) {
    __hip_bfloat16 b = __float2bfloat16(f[i]);
    o[i] = *(unsigned short*)&b;
  }
  *(us8*)(outb + (size_t)gw * K + lane * 8) = o;
#pragma unroll
  for (int off = 32; off > 0; off >>= 1) ss += __shfl_down(ss, off, 64);
  if (lane == 0) norms[gw] = 1.0f / fmaxf(sqrtf(ss), 1e-4f);
}

// Persistent drain-interleaved GEMM. 256 blocks (1/CU), 512 thr / 8 waves.
// XCD x owns rows [x*1024, x*1024+1024): per-XCD L2 set = A 1MB + B 1MB.
// Block: fixed 256-row strip, walks 8 col-tiles (panel c0+8t). Per K-step:
// {stage A(s+1)+B(g+2); FENCE; drain 1 frag of prev tile; ds_read 8 frags;
// 16 MFMA; vmcnt(5); barrier}. Stores spread uniformly -> overlap with MFMA.
__global__ __launch_bounds__(512, 2) void gemm_kernel(const unsigned short* __restrict__ A,
                                                      const unsigned short* __restrict__ B,
                                                      const float* __restrict__ iw1,
                                                      const float* __restrict__ iw2,
                                                      float* __restrict__ C) {
  __shared__ __align__(128) unsigned short As[2][BM * BK];  // 2 x 16 KB
  __shared__ __align__(128) unsigned short Bs[3][BN * BK];  // 3 x 8 KB

  const int tid = threadIdx.x;
  const int wave = tid >> 6;
  const int lane = tid & 63;
  const int wr = wave >> 1;  // 0..3 : M strip of 64
  const int wc = wave & 1;   // 0..1 : N strip of 64
  const int fr = lane & 15;
  const int fq = lane >> 4;

  const int xcd = blockIdx.x & 7;
  const int kk = blockIdx.x >> 3;               // 0..31
  const int bRow = (xcd * 4 + (kk >> 3)) * BM;  // XCD-local row strip
  const int c0 = kk & 7;                        // col panel start
  auto colOf = [&](int t) { return (c0 + 8 * t) * BN; };

  const int srow = lane >> 2;       // 0..15
  const int scol = (lane & 3) * 8;  // bf16 col offset

  auto stageA = [&](int buf, int sl) {
#pragma unroll
    for (int c = 0; c < 2; ++c)
      gload_lds16(A + (size_t)(bRow + c * 128 + wave * 16 + srow) * K + sl * BK + scol,
                  (char*)&As[buf][0] + (c * 128 + wave * 16) * 64);
  };
  auto stageB = [&](int buf, int bCol, int sl) {
    gload_lds16(B + (size_t)(bCol + wave * 16 + srow) * K + sl * BK + scol,
                (char*)&Bs[buf][0] + wave * 16 * 64);
  };
  auto ldA = [&](int buf, int r) -> bf16x8 {
    return *(const bf16x8*)((const char*)&As[buf][0] + r * 64 + fq * 16);
  };
  auto ldB = [&](int buf, int r) -> bf16x8 {
    return *(const bf16x8*)((const char*)&Bs[buf][0] + r * 64 + fq * 16);
  };

  float i1v[4][4];
#pragma unroll
  for (int m = 0; m < 4; ++m)
#pragma unroll
    for (int r = 0; r < 4; ++r) i1v[m][r] = iw1[bRow + wr * 64 + m * 16 + fq * 4 + r];

  f32x4 accA[4][4] = {}, accB[4][4] = {};
  float i2A[4] = {}, i2B[4] = {};

  // Prologue: A(0) [2], B(g=0) [1], B(g=1) [1] -> need A0,B0 landed.
  stageA(0, 0);
  stageB(0, colOf(0), 0);
  stageB(1, colOf(0), 1);
  asm volatile("s_waitcnt vmcnt(1)" ::: "memory");
  BARRIER();

  // One tile: accumulate `acc` over 16 K-steps; drain `prev` one frag/step.
  // Fake-drain (first call: prev=zeros -> tile7 addrs) keeps FIFO uniform;
  // tail overwrites those addresses (same lanes, program order).
  auto tile_body = [&](f32x4 (&acc)[4][4], float (&i2)[4],
                       f32x4 (&prev)[4][4], float (&i2p)[4],
                       int t, int colCur, int colPrev, bool last) {
#pragma unroll
    for (int n = 0; n < 4; ++n) i2[n] = iw2[colCur + wc * 64 + n * 16 + fr];
#pragma unroll
    for (int m = 0; m < 4; ++m)
#pragma unroll
      for (int n = 0; n < 4; ++n) acc[m][n] = (f32x4){0.f, 0.f, 0.f, 0.f};

#pragma unroll
    for (int s = 0; s < NS; ++s) {
      const int cur = s & 1, nxt = cur ^ 1;
      const int g = t * NS + s;

      stageA(nxt, (s + 1) & 15);  // 2 gloads (wraps: next tile reuses A)
      if (!last || s < 14) {      // 1 gload: B for step g+2
        const int g2 = g + 2;
        stageB(g2 % 3, (c0 + 8 * (g2 >> 4)) * BN, g2 & 15);
      }
      MEMFENCE();  // loads precede stores in the VMEM FIFO
      {
        const int dm = s >> 2, dn = s & 3;
        const int col = colPrev + wc * 64 + dn * 16 + fr;
        const int row0 = bRow + wr * 64 + dm * 16 + fq * 4;
#pragma unroll
        for (int r = 0; r < 4; ++r)
          C[(size_t)(row0 + r) * N + col] = prev[dm][dn][r] * i1v[dm][r] * i2p[dn];
      }

      bf16x8 a[4], b[4];
#pragma unroll
      for (int m = 0; m < 4; ++m) a[m] = ldA(cur, wr * 64 + m * 16 + fr);
      const int bc = g % 3;
#pragma unroll
      for (int n = 0; n < 4; ++n) b[n] = ldB(bc, wc * 64 + n * 16 + fr);

      __builtin_amdgcn_s_setprio(1);
#pragma unroll
      for (int m = 0; m < 4; ++m)
#pragma unroll
        for (int n = 0; n < 4; ++n)
          acc[m][n] = __builtin_amdgcn_mfma_f32_16x16x32_bf16(a[m], b[n], acc[m][n], 0, 0, 0);
      __builtin_amdgcn_s_setprio(0);

      if (!last || s < 14) {
        // FIFO: [B(g+1)][st_old x4][A x2][B(g+2)][st x4] -> vmcnt(5)
        // completes all loads step g+1 needs, leaves B(g+2)+stores in flight.
        asm volatile("s_waitcnt vmcnt(5)" ::: "memory");
      } else if (s == 14) {
        // FIFO: [B(127)][st x4][A x2][st x4] -> vmcnt(4) completes B+A.
        asm volatile("s_waitcnt vmcnt(4)" ::: "memory");
      }  // s==15 of last tile: nothing left to wait for
      BARRIER();
    }
  };

  // 8 tiles as 4 pairs; accA/accB alternate (static names, rule #20).
#pragma clang loop unroll(disable)
  for (int p = 0; p < 4; ++p) {
    const int tE = 2 * p, tO = 2 * p + 1;
    tile_body(accA, i2A, accB, i2B, tE, colOf(tE), p ? colOf(tE - 1) : colOf(7), false);
    tile_body(accB, i2B, accA, i2A, tO, colOf(tO), colOf(tE), tO == 7);
  }

  // Tail: drain tile 7 (accB) — overwrites the fake-drain zeros.
#pragma unroll
  for (int dm = 0; dm < 4; ++dm) {
    const int row0 = bRow + wr * 64 + dm * 16 + fq * 4;
#pragma unroll
    for (int dn = 0; dn < 4; ++dn) {
      const int col = colOf(7) + wc * 64 + dn * 16 + fr;
#pragma unroll
      for (int r = 0; r < 4; ++r)
        C[(size_t)(row0 + r) * N + col] = accB[dm][dn][r] * i1v[dm][r] * i2B[dn];
    }
  }
}

extern "C" void kernel_launch(void* const* d_in, const int* in_sizes, int n_in,
                              void* d_out, int out_size, void* d_ws, size_t ws_size,
                              hipStream_t stream) {
  (void)in_sizes; (void)n_in; (void)out_size; (void)ws_size;
  const float* img = (const float*)d_in[0];
  const float* txt = (const float*)d_in[1];
  float* out = (float*)d_out;

  unsigned short* Abf = (unsigned short*)d_ws;
  unsigned short* Bbf = Abf + (size_t)M * K;
  float* w1 = (float*)(Bbf + (size_t)N * K);
  float* w2 = w1 + M;

  prep_kernel<<<4096, 256, 0, stream>>>(img, txt, Abf, Bbf, w1, w2);
  gemm_kernel<<<256, 512, 0, stream>>>(Abf, Bbf, w1, w2, out);
}

// Round 9
// 109.183 us; speedup vs baseline: 1.9887x; 1.9887x over previous
//
#include <hip/hip_runtime.h>
#include <hip/hip_bf16.h>

#define M 8192
#define N 8192
#define K 512
#define BM 128
#define BN 128
#define BK 32
#define NT (K / BK)  // 16 K-steps

typedef __attribute__((ext_vector_type(8))) short bf16x8;
typedef __attribute__((ext_vector_type(4))) float f32x4;
typedef __attribute__((ext_vector_type(8))) unsigned short us8;

__device__ inline void gload_lds16(const void* g, void* l) {
  __builtin_amdgcn_global_load_lds(
      (const __attribute__((address_space(1))) unsigned int*)g,
      (__attribute__((address_space(3))) unsigned int*)l, 16, 0, 0);
}

#define BARRIER()                          \
  do {                                     \
    asm volatile("" ::: "memory");         \
    __builtin_amdgcn_s_barrier();          \
    asm volatile("" ::: "memory");         \
  } while (0)

// Fused prep: cast f32 rows -> bf16, store INVERSE L2 norm (1/max(norm,1e-4)).
// Norms are ~sqrt(512); inv1*inv2 == 1/max(w1*w2,1e-8) exactly here.
__global__ __launch_bounds__(256) void prep_kernel(const float* __restrict__ img,
                                                   const float* __restrict__ txt,
                                                   unsigned short* __restrict__ Abf,
                                                   unsigned short* __restrict__ Bbf,
                                                   float* __restrict__ w1,
                                                   float* __restrict__ w2) {
  const int half = blockIdx.x >> 11;
  const int lb = blockIdx.x & 2047;
  const float* in = half ? txt : img;
  unsigned short* outb = half ? Bbf : Abf;
  float* norms = half ? w2 : w1;

  const int gw = (lb * 256 + threadIdx.x) >> 6;
  const int lane = threadIdx.x & 63;
  const float4* rp4 = (const float4*)(in + (size_t)gw * K);
  float4 v0 = rp4[lane * 2];
  float4 v1 = rp4[lane * 2 + 1];
  float ss = v0.x * v0.x + v0.y * v0.y + v0.z * v0.z + v0.w * v0.w +
             v1.x * v1.x + v1.y * v1.y + v1.z * v1.z + v1.w * v1.w;
  float f[8] = {v0.x, v0.y, v0.z, v0.w, v1.x, v1.y, v1.z, v1.w};
  us8 o;
#pragma unroll
  for (int i = 0; i < 8; ++i) {
    __hip_bfloat16 b = __float2bfloat16(f[i]);
    o[i] = *(unsigned short*)&b;
  }
  *(us8*)(outb + (size_t)gw * K + lane * 8) = o;
#pragma unroll
  for (int off = 32; off > 0; off >>= 1) ss += __shfl_down(ss, off, 64);
  if (lane == 0) norms[gw] = 1.0f / fmaxf(sqrtf(ss), 1e-4f);
}

// 128x128 bf16 GEMM, BK=32, 4 waves (wave tile 64x64), 4 blocks/CU.
// One barrier per K-step: {stage A(t+1)+B(t+2); ds_read 8 frags; 16 MFMA;
// counted vmcnt; barrier}. Natural inter-block desync overlaps epilogue
// store bursts with other blocks' K-loops.
// LDS bank swizzle: 16B granule slot j' = j ^ ((r>>1)&3) -> the 8 lanes of
// each issue group start at 8 distinct dword-banks covering all 32 banks.
// Applied to gload SOURCE col (LDS dest linear, rule #21) and ds_read addr.
__global__ __launch_bounds__(256, 4) void gemm_kernel(const unsigned short* __restrict__ A,
                                                      const unsigned short* __restrict__ B,
                                                      const float* __restrict__ iw1,
                                                      const float* __restrict__ iw2,
                                                      float* __restrict__ C) {
  __shared__ __align__(128) unsigned short As[2][BM * BK];  // 2 x 8 KB
  __shared__ __align__(128) unsigned short Bs[3][BN * BK];  // 3 x 8 KB

  const int tid = threadIdx.x;
  const int wave = tid >> 6;  // 0..3
  const int lane = tid & 63;
  const int wr = wave >> 1;  // 0..1 : M strip of 64
  const int wc = wave & 1;   // 0..1 : N strip of 64
  const int fr = lane & 15;
  const int fq = lane >> 4;

  // Two-level swizzle: xcd owns col-panels [xcd*8, xcd*8+8) (B window 1 MB,
  // L2-resident); idx>>3 walks 64 row-panels (concurrent A window ~2 MB).
  const int xcd = blockIdx.x & 7;
  const int idx = blockIdx.x >> 3;              // 0..511
  const int bRow = (idx >> 3) * BM;             // 64 row-panels of 128
  const int bCol = (xcd * 8 + (idx & 7)) * BN;  // 64 col-panels of 128

  // Staging: each wave covers 16 rows x 64B per call; source granule
  // pre-swizzled so LDS slot jl holds global granule jl ^ ((row>>1)&3).
  const int srow = lane >> 2;                                   // 0..15
  const int scol = (((lane & 3) ^ ((srow >> 1) & 3)) * 8);      // bf16 offset

  auto stageA = [&](int buf, int kt) {
#pragma unroll
    for (int c = 0; c < 2; ++c)
      gload_lds16(A + (size_t)(bRow + c * 64 + wave * 16 + srow) * K + kt * BK + scol,
                  (char*)&As[buf][0] + (c * 64 + wave * 16) * 64);
  };
  auto stageB = [&](int buf, int kt) {
#pragma unroll
    for (int c = 0; c < 2; ++c)
      gload_lds16(B + (size_t)(bCol + c * 64 + wave * 16 + srow) * K + kt * BK + scol,
                  (char*)&Bs[buf][0] + (c * 64 + wave * 16) * 64);
  };
  auto ldA = [&](int buf, int r) -> bf16x8 {
    return *(const bf16x8*)((const char*)&As[buf][0] + r * 64 +
                            ((fq ^ ((r >> 1) & 3)) * 16));
  };
  auto ldB = [&](int buf, int r) -> bf16x8 {
    return *(const bf16x8*)((const char*)&Bs[buf][0] + r * 64 +
                            ((fq ^ ((r >> 1) & 3)) * 16));
  };

  f32x4 acc[4][4] = {};

  // Prologue: A(0) x2, B(0) x2, B(1) x2 -> need A0,B0 landed, B1 in flight.
  stageA(0, 0);
  stageB(0, 0);
  stageB(1, 1);
  asm volatile("s_waitcnt vmcnt(2)" ::: "memory");
  BARRIER();

#pragma unroll
  for (int t = 0; t < NT; ++t) {
    const int cur = t & 1, nxt = cur ^ 1;
    const int bc = t % 3, b2 = (t + 2) % 3;

    if (t + 1 < NT) stageA(nxt, t + 1);  // 2 gloads
    if (t + 2 < NT) stageB(b2, t + 2);   // 2 gloads

    bf16x8 a[4], b[4];
#pragma unroll
    for (int m = 0; m < 4; ++m) a[m] = ldA(cur, wr * 64 + m * 16 + fr);
#pragma unroll
    for (int n = 0; n < 4; ++n) b[n] = ldB(bc, wc * 64 + n * 16 + fr);

    __builtin_amdgcn_s_setprio(1);
#pragma unroll
    for (int m = 0; m < 4; ++m)
#pragma unroll
      for (int n = 0; n < 4; ++n)
        acc[m][n] = __builtin_amdgcn_mfma_f32_16x16x32_bf16(a[m], b[n], acc[m][n], 0, 0, 0);
    __builtin_amdgcn_s_setprio(0);

    if (t < NT - 2) {
      // FIFO at wait: [B(t+1)x2][A(t+1)x2][B(t+2)x2] -> vmcnt(2) lands all
      // of step t+1's data, leaves B(t+2) in flight.
      asm volatile("s_waitcnt vmcnt(2)" ::: "memory");
    } else if (t == NT - 2) {
      asm volatile("s_waitcnt vmcnt(0)" ::: "memory");
    }
    BARRIER();
  }

  // Epilogue. C/D layout: col = lane&15, row = (lane>>4)*4 + reg.
  float i1v[4][4], i2v[4];
#pragma unroll
  for (int m = 0; m < 4; ++m)
#pragma unroll
    for (int r = 0; r < 4; ++r) i1v[m][r] = iw1[bRow + wr * 64 + m * 16 + fq * 4 + r];
#pragma unroll
  for (int n = 0; n < 4; ++n) i2v[n] = iw2[bCol + wc * 64 + n * 16 + fr];

#pragma unroll
  for (int m = 0; m < 4; ++m) {
    const int row0 = bRow + wr * 64 + m * 16 + fq * 4;
#pragma unroll
    for (int n = 0; n < 4; ++n) {
      const int col = bCol + wc * 64 + n * 16 + fr;
      f32x4 v = acc[m][n];
#pragma unroll
      for (int r = 0; r < 4; ++r)
        C[(size_t)(row0 + r) * N + col] = v[r] * i1v[m][r] * i2v[n];
    }
  }
}

extern "C" void kernel_launch(void* const* d_in, const int* in_sizes, int n_in,
                              void* d_out, int out_size, void* d_ws, size_t ws_size,
                              hipStream_t stream) {
  (void)in_sizes; (void)n_in; (void)out_size; (void)ws_size;
  const float* img = (const float*)d_in[0];
  const float* txt = (const float*)d_in[1];
  float* out = (float*)d_out;

  unsigned short* Abf = (unsigned short*)d_ws;
  unsigned short* Bbf = Abf + (size_t)M * K;
  float* w1 = (float*)(Bbf + (size_t)N * K);
  float* w2 = w1 + M;

  prep_kernel<<<4096, 256, 0, stream>>>(img, txt, Abf, Bbf, w1, w2);
  gemm_kernel<<<(M / BM) * (N / BN), 256, 0, stream>>>(Abf, Bbf, w1, w2, out);
}